// Round 6
// baseline (746.062 us; speedup 1.0000x reference)
//
#include <hip/hip_runtime.h>

#define N_    16
#define CIN_  64
#define HW_   56
#define COUT_ 64
#define HPR   58                 // padded rows
#define WST   60                 // padded row stride (dwords)
#define PLANE_PAD 3584           // 14 chunks of 256 dwords (64 lanes x 16B)

// ---- kernel 1: zero-padded copy of x into ws: xp[n][ci][3584] ----
__global__ void pad_x_kernel(const float* __restrict__ x, float* __restrict__ xp) {
    int idx = blockIdx.x * 256 + threadIdx.x;
    const int total = N_ * CIN_ * PLANE_PAD;
    if (idx >= total) return;
    int rem = idx % PLANE_PAD;
    int nc  = idx / PLANE_PAD;
    int h   = rem / WST;
    int w   = rem % WST;
    float v = 0.f;
    if (h >= 1 && h <= HW_ && w >= 1 && w <= HW_)
        v = x[((size_t)nc * HW_ + (h - 1)) * HW_ + (w - 1)];
    xp[idx] = v;
}

// ---- kernel 2: main AdderNet kernel ----
// Grid 1024 = (n:16, co-quad:16, ci-chunk:4).  Block 256 thr = 4 waves.
// Wave wid -> co = quad*4+wid; ALL waves consume the SAME staged ci plane
// per iter (16 iters, ci = chunk*16+it), so LDS = 2 x 1 plane = 28.7KB ->
// 4 blocks/CU -> 4 waves/SIMD (2x round-5 TLP; R5's 57KB capped at 2/SIMD).
// ci-chunks of one (n,co) live in 4 blocks -> fire-and-forget atomicAdd
// into zeroed out (4 adds/elem; no LDS reduction, no extra ws).
__global__ __launch_bounds__(256, 4) void adder_main_kernel(
    const float* __restrict__ xp, const float* __restrict__ wt,
    float* __restrict__ out) {
    __shared__ float lds[2][PLANE_PAD];   // 28,672 B

    const int bid   = blockIdx.x;         // n*64 + quad*4 + chunk
    const int n     = bid >> 6;
    const int quad  = (bid >> 2) & 15;
    const int chunk = bid & 3;
    const int tid   = threadIdx.x;
    const int wid   = tid >> 6;           // wave id 0..3 -> co within quad
    const int lane  = tid & 63;
    const int co    = quad * 4 + wid;
    const int ci0   = chunk * 16;
    const int tx = lane & 7, ty = lane >> 3;
    const int h0 = ty * 7, w0 = tx * 7;
    const int rb = h0 * WST + w0;

    const float* gplane = xp + (size_t)(n * CIN_ + ci0) * PLANE_PAD;
    const float* wbase  = wt + (size_t)co * 576 + (size_t)ci0 * 9;

    // one plane = 14 chunks of (64 lanes x 16B); wave wid stages chunks
    // {wid, wid+4, wid+8, wid+12} (waves 0,1: 4 chunks; 2,3: 3).
    #define STAGEP(bufi, i_) { \
        const float* gsrc_ = gplane + (size_t)(i_) * PLANE_PAD; \
        _Pragma("unroll") \
        for (int k_ = 0; k_ < 4; ++k_) { \
            int c_ = wid + 4 * k_; \
            if (c_ < 14) \
                __builtin_amdgcn_global_load_lds( \
                    (const __attribute__((address_space(1))) void*)(gsrc_ + c_ * 256 + lane * 4), \
                    (__attribute__((address_space(3))) void*)(&lds[bufi][c_ * 256]), 16, 0, 0); \
        } }

    float acc[7][7] = {};

    STAGEP(0, 0)                 // prologue
    __syncthreads();

    for (int it = 0; it < 16; ++it) {
        const int cur = it & 1;
        if (it < 15) STAGEP(cur ^ 1, it + 1)   // lands during compute

        const float* wp = wbase + it * 9;      // wave-uniform -> s_load
        float w9[9];
        #pragma unroll
        for (int k = 0; k < 9; ++k) w9[k] = wp[k];

        float buf[9][9];   // rolling window, static indices only
        #define LROW(r) { _Pragma("unroll") \
            for (int c = 0; c < 9; ++c) buf[r][c] = lds[cur][rb + (r) * WST + c]; }
        #define CROW(oh) { _Pragma("unroll") \
            for (int kh = 0; kh < 3; ++kh) { \
                _Pragma("unroll") \
                for (int kw = 0; kw < 3; ++kw) { \
                    float wv = w9[kh * 3 + kw]; \
                    _Pragma("unroll") \
                    for (int j = 0; j < 7; ++j) \
                        acc[oh][j] += fabsf(buf[(oh) + kh][j + kw] - wv); \
                } } }

        LROW(0) LROW(1) LROW(2) LROW(3)
        CROW(0) LROW(4)
        CROW(1) LROW(5)
        CROW(2) LROW(6)
        CROW(3) LROW(7)
        CROW(4) LROW(8)
        CROW(5)
        CROW(6)
        #undef LROW
        #undef CROW

        __syncthreads();
    }

    // epilogue: 49 fire-and-forget atomics/lane into zero-initialized out
    float* ob = out + (((size_t)(n * COUT_ + co)) * HW_ + h0) * HW_ + w0;
    #pragma unroll
    for (int oh = 0; oh < 7; ++oh)
        #pragma unroll
        for (int j = 0; j < 7; ++j)
            atomicAdd(&ob[oh * HW_ + j], -acc[oh][j]);
    #undef STAGEP
}

extern "C" void kernel_launch(void* const* d_in, const int* in_sizes, int n_in,
                              void* d_out, int out_size, void* d_ws, size_t ws_size,
                              hipStream_t stream) {
    const float* x     = (const float*)d_in[0];
    const float* adder = (const float*)d_in[1];
    float* out = (float*)d_out;

    float* xp = (float*)d_ws;   // 16*64*3584*4 = 14.68 MB of ws

    hipMemsetAsync(d_out, 0, (size_t)out_size * sizeof(float), stream);
    const int padTotal = N_ * CIN_ * PLANE_PAD;
    pad_x_kernel<<<(padTotal + 255) / 256, 256, 0, stream>>>(x, xp);
    adder_main_kernel<<<N_ * 64, 256, 0, stream>>>(xp, adder, out);
}

// Round 7
// 195.108 us; speedup vs baseline: 3.8238x; 3.8238x over previous
//
#include <hip/hip_runtime.h>

#define N_    16
#define CIN_  64
#define HW_   56
#define COUT_ 64
#define WST   60                 // padded row stride (dwords)
#define PLANE_PAD 3584           // plane stride (14 x 256 dwords)
#define STAGE_DW 768             // 3 chunks of 256 dwords (10-row band + slack)

// ---- kernel 1: zero-padded copy of x into ws: xp[n][ci][3584] ----
__global__ void pad_x_kernel(const float* __restrict__ x, float* __restrict__ xp) {
    int idx = blockIdx.x * 256 + threadIdx.x;
    const int total = N_ * CIN_ * PLANE_PAD;
    if (idx >= total) return;
    int rem = idx % PLANE_PAD;
    int nc  = idx / PLANE_PAD;
    int h   = rem / WST;
    int w   = rem % WST;
    float v = 0.f;
    if (h >= 1 && h <= HW_ && w >= 1 && w <= HW_)
        v = x[((size_t)nc * HW_ + (h - 1)) * HW_ + (w - 1)];
    xp[idx] = v;
}

// ---- kernel 2: main AdderNet kernel ----
// Thread = one 7-wide output strip of one row: state = acc[7] + 27 input
// floats + 9 weights ~= 55 VGPR. R3/R4/R6 lesson: the 9x9 register window
// is regalloc-fragile (spill or load-sinking, bimodally); this shape has
// nothing to spill.  Block = 4 waves = 4 co sharing one staged 10-row band
// (LDS 2x3KB); lane = (ty: 8 rows, tx: 8 strips).  Grid = 16n x 16quad x
// 7slices = 1792 blocks = 7 blocks/CU = 28 waves/CU -> 7 waves/SIMD of
// latency cover (R5 had only 2).  Full ci loop in-block -> direct stores.
__global__ __launch_bounds__(256, 7) void adder_main_kernel(
    const float* __restrict__ xp, const float* __restrict__ wt,
    float* __restrict__ out) {
    __shared__ float lds[2][STAGE_DW];   // 6144 B

    const int bid   = blockIdx.x;        // n*112 + quad*7 + slice
    const int n     = bid / 112;
    const int rq    = bid % 112;
    const int quad  = rq / 7;
    const int slice = rq % 7;
    const int tid   = threadIdx.x;
    const int wid   = tid >> 6;          // wave id 0..3 -> co within quad
    const int lane  = tid & 63;
    const int co    = quad * 4 + wid;
    const int tx = lane & 7, ty = lane >> 3;
    const int h0 = slice * 8;            // first output row of this slice
    // staging origin (dwords, 16B-aligned); slice 6 shifted so 768-dword
    // stage ends exactly at the 3584 plane edge.
    const int sbase = (slice == 6) ? 2816 : h0 * WST;
    const int rb    = h0 * WST - sbase + ty * WST + tx * 7;  // lane's LDS base

    const float* wbase = wt + (size_t)co * 576;   // adder[co] contiguous
    const size_t gp0   = (size_t)(n * CIN_) * PLANE_PAD + sbase;

    // 3 chunks of (64 lanes x 16B) per plane-band; waves 0..2 issue one each.
    #define STAGEP(bufi, ci_) \
        if (wid < 3) { \
            __builtin_amdgcn_global_load_lds( \
                (const __attribute__((address_space(1))) void*)(xp + gp0 + (size_t)(ci_) * PLANE_PAD + wid * 256 + lane * 4), \
                (__attribute__((address_space(3))) void*)(&lds[bufi][wid * 256]), 16, 0, 0); \
        }

    float acc[7] = {};

    STAGEP(0, 0)                 // prologue
    __syncthreads();

    for (int it = 0; it < CIN_; ++it) {
        const int cur = it & 1;
        if (it < CIN_ - 1) STAGEP(cur ^ 1, it + 1)   // lands during compute

        const float* wp = wbase + it * 9;            // wave-uniform -> s_load
        float w9[9];
        #pragma unroll
        for (int k = 0; k < 9; ++k) w9[k] = wp[k];

        const float* lp = &lds[cur][rb];
        float r0[9], r1[9], r2[9];                   // the 3 input rows
        #pragma unroll
        for (int c = 0; c < 9; ++c) r0[c] = lp[c];
        #pragma unroll
        for (int c = 0; c < 9; ++c) r1[c] = lp[WST + c];
        #pragma unroll
        for (int c = 0; c < 9; ++c) r2[c] = lp[2 * WST + c];

        #pragma unroll
        for (int kw = 0; kw < 3; ++kw) {
            const float wv0 = w9[kw], wv1 = w9[3 + kw], wv2 = w9[6 + kw];
            #pragma unroll
            for (int j = 0; j < 7; ++j) {
                acc[j] += fabsf(r0[j + kw] - wv0);
                acc[j] += fabsf(r1[j + kw] - wv1);
                acc[j] += fabsf(r2[j + kw] - wv2);
            }
        }

        __syncthreads();   // staging of cur^1 complete; reads of cur done
    }
    #undef STAGEP

    float* ob = out + (((size_t)(n * COUT_ + co)) * HW_ + (h0 + ty)) * HW_ + tx * 7;
    #pragma unroll
    for (int j = 0; j < 7; ++j) ob[j] = -acc[j];
}

extern "C" void kernel_launch(void* const* d_in, const int* in_sizes, int n_in,
                              void* d_out, int out_size, void* d_ws, size_t ws_size,
                              hipStream_t stream) {
    const float* x     = (const float*)d_in[0];
    const float* adder = (const float*)d_in[1];
    float* out = (float*)d_out;

    float* xp = (float*)d_ws;   // 16*64*3584*4 = 14.68 MB of ws

    const int padTotal = N_ * CIN_ * PLANE_PAD;
    pad_x_kernel<<<(padTotal + 255) / 256, 256, 0, stream>>>(x, xp);
    adder_main_kernel<<<N_ * 112, 256, 0, stream>>>(xp, adder, out);
}